// Round 5
// baseline (391.172 us; speedup 1.0000x reference)
//
#include <hip/hip_runtime.h>
#include <hip/hip_fp16.h>
#include <math.h>

// Problem constants (match reference)
#define NN   100000
#define EE   3200000
#define GG   512
#define INC  128
#define D1   64        // H1*C1 = 8*8
#define OUTC 64
#define HID  128
#define NEG  0.2f

// Two-level CSR binning
#define BINS 391       // ceil(NN/256)
#define BCAP 9216      // Poisson(8192) + 11 sigma; overflow-guarded
#define BKBLK 1563     // ceil(EE/2048) bucket blocks in the fused kernel
#define NGB 391        // ceil(NN/256) register-tiled GEMM blocks

typedef __attribute__((ext_vector_type(2))) float v2f;

// ===========================================================================
// FUSED: [blocks 0..NGB) = lin1 GEMM (long blocks, launched first)
//        [NGB..NGB+BKBLK) = bucket scatter (short, fills remaining slots).
// lin1 is a register-tiled 8x8 GEMM: 256 nodes/block, thread = 8 rows x 8
// cols, per-k LDS = 4x ds_read_b128 for 64 FMAs.
// ===========================================================================
__global__ __launch_bounds__(256, 3)
void k_fused(const int* __restrict__ srcv, const int* __restrict__ dstv,
             int* __restrict__ cursor, int* __restrict__ bucket,
             const float* __restrict__ x, const float* __restrict__ W1,
             const float* __restrict__ att_s, const float* __restrict__ att_d,
             unsigned int* __restrict__ h1, __half* __restrict__ a_s,
             float* __restrict__ a_d) {
    __shared__ __align__(16) char smem[49152];
    int tid = threadIdx.x;
    if (blockIdx.x < NGB) {
        // ---------------- lin1: h1 = x @ W1 (fp8 store), attention dots ----
        float4* sW4 = (float4*)smem;                        // 32768 B
        float (*sxT)[256] = (float(*)[256])(smem + 32768);  // 16x256x4 = 16384 B
        const float4* W4 = (const float4*)W1;
        for (int i = tid; i < 128 * 16; i += 256) sW4[i] = W4[i];
        int node0 = blockIdx.x * 256;
        int rg = tid >> 3, cg = tid & 7;     // 32 row-groups x 8 col-groups
        float acc[8][8];
#pragma unroll
        for (int ii = 0; ii < 8; ++ii)
#pragma unroll
            for (int jj = 0; jj < 8; ++jj) acc[ii][jj] = 0.f;
        const float4* x4 = (const float4*)x;
        for (int kt = 0; kt < 8; ++kt) {     // K tiles of 16
            if (kt) __syncthreads();         // readers done with prev tile
#pragma unroll
            for (int q = 0; q < 4; ++q) {    // stage 256 rows x 16 k, transposed
                int i = q * 256 + tid;
                int r = i >> 2, kc = i & 3;
                int gn = node0 + r;
                float4 v = {0.f, 0.f, 0.f, 0.f};
                if (gn < NN) v = x4[(size_t)gn * 32 + kt * 4 + kc];
                int cs = r ^ (kc << 3);      // swizzle: s = (k>>2)<<3, k>>2 = kc
                sxT[kc * 4 + 0][cs] = v.x;
                sxT[kc * 4 + 1][cs] = v.y;
                sxT[kc * 4 + 2][cs] = v.z;
                sxT[kc * 4 + 3][cs] = v.w;
            }
            __syncthreads();
#pragma unroll 4
            for (int kk = 0; kk < 16; ++kk) {
                int sw = (kk >> 2) << 3;
                const float* xr = &sxT[kk][(rg * 8) ^ sw];
                float4 xa = *(const float4*)xr;
                float4 xb = *(const float4*)(xr + 4);
                int kg = kt * 16 + kk;
                float4 wa = sW4[kg * 16 + cg * 2];
                float4 wb = sW4[kg * 16 + cg * 2 + 1];
                float xv[8] = {xa.x, xa.y, xa.z, xa.w, xb.x, xb.y, xb.z, xb.w};
                float wv[8] = {wa.x, wa.y, wa.z, wa.w, wb.x, wb.y, wb.z, wb.w};
#pragma unroll
                for (int ii = 0; ii < 8; ++ii)
#pragma unroll
                    for (int jj = 0; jj < 8; ++jj)
                        acc[ii][jj] = fmaf(xv[ii], wv[jj], acc[ii][jj]);
            }
        }
        // epilogue: fp8 pack + per-head attention dots (head == cg, no reduce)
        float4 s0 = ((const float4*)att_s)[cg * 2];
        float4 s1 = ((const float4*)att_s)[cg * 2 + 1];
        float4 d0 = ((const float4*)att_d)[cg * 2];
        float4 d1 = ((const float4*)att_d)[cg * 2 + 1];
        uint2* hp2 = (uint2*)h1;
#pragma unroll
        for (int ii = 0; ii < 8; ++ii) {
            int n = node0 + rg * 8 + ii;
            if (n < NN) {
                float* a = acc[ii];
                int p0 = __builtin_amdgcn_cvt_pk_fp8_f32(a[0], a[1], 0, false);
                p0 = __builtin_amdgcn_cvt_pk_fp8_f32(a[2], a[3], p0, true);
                int p1 = __builtin_amdgcn_cvt_pk_fp8_f32(a[4], a[5], 0, false);
                p1 = __builtin_amdgcn_cvt_pk_fp8_f32(a[6], a[7], p1, true);
                uint2 pk; pk.x = (unsigned)p0; pk.y = (unsigned)p1;
                hp2[n * 8 + cg] = pk;
                float as = a[0] * s0.x;
                as = fmaf(a[1], s0.y, as); as = fmaf(a[2], s0.z, as);
                as = fmaf(a[3], s0.w, as); as = fmaf(a[4], s1.x, as);
                as = fmaf(a[5], s1.y, as); as = fmaf(a[6], s1.z, as);
                as = fmaf(a[7], s1.w, as);
                float ad = a[0] * d0.x;
                ad = fmaf(a[1], d0.y, ad); ad = fmaf(a[2], d0.z, ad);
                ad = fmaf(a[3], d0.w, ad); ad = fmaf(a[4], d1.x, ad);
                ad = fmaf(a[5], d1.y, ad); ad = fmaf(a[6], d1.z, ad);
                ad = fmaf(a[7], d1.w, ad);
                a_s[n * 8 + cg] = __float2half(as);
                a_d[n * 8 + cg] = ad;
            }
        }
    } else {
        // ---------------- bucket scatter ----------------
        int* hcnt  = (int*)smem;          // BINS
        int* hbase = hcnt + BINS;         // BINS
        for (int i = tid; i < BINS; i += 256) hcnt[i] = 0;
        __syncthreads();
        int e0 = (blockIdx.x - NGB) * 2048;
        int bn[8], rk[8], pk[8];
#pragma unroll
        for (int q = 0; q < 8; ++q) {
            int e = e0 + q * 256 + tid;
            if (e < EE) {
                int s = srcv[e], d = dstv[e];
                bn[q] = d >> 8;
                pk[q] = (s << 8) | (d & 255);
                rk[q] = atomicAdd(&hcnt[bn[q]], 1);   // LDS atomic
            } else bn[q] = -1;
        }
        __syncthreads();
        for (int i = tid; i < BINS; i += 256) {
            int c = hcnt[i];
            hbase[i] = c ? atomicAdd(&cursor[i], c) : 0;
        }
        __syncthreads();
#pragma unroll
        for (int q = 0; q < 8; ++q) {
            if (bn[q] >= 0) {
                int p = hbase[bn[q]] + rk[q];
                if (p < BCAP) bucket[bn[q] * BCAP + p] = pk[q];
            }
        }
    }
}

// ===========================================================================
// P3: per-bin fine CSR. One block per bin (256 nodes). Two streaming passes
// over the bin segment (sits in L2): LDS hist+scan -> rbeg/rend; scatter col.
// ===========================================================================
__global__ __launch_bounds__(256)
void k_binCSR(const int* __restrict__ cursor, const int* __restrict__ bucket,
              int* __restrict__ col, int* __restrict__ rbeg, int* __restrict__ rend) {
    __shared__ int cnt[256];
    __shared__ int tmp[256];
    __shared__ int cur[256];
    int b = blockIdx.x, tid = threadIdx.x;
    cnt[tid] = 0;
    __syncthreads();
    int m = cursor[b]; if (m > BCAP) m = BCAP;
    const int* seg = bucket + b * BCAP;
    for (int i = tid; i < m; i += 256)
        atomicAdd(&cnt[seg[i] & 255], 1);
    __syncthreads();
    tmp[tid] = cnt[tid];
    __syncthreads();
    for (int off = 1; off < 256; off <<= 1) {
        int t = (tid >= off) ? tmp[tid - off] : 0;
        __syncthreads();
        tmp[tid] += t;
        __syncthreads();
    }
    int excl = tmp[tid] - cnt[tid];
    int n = b * 256 + tid;
    if (n < NN) {
        rbeg[n] = b * BCAP + excl;
        rend[n] = b * BCAP + excl + cnt[tid];
    }
    cur[tid] = excl;
    __syncthreads();
    for (int i = tid; i < m; i += 256) {
        int pkv = seg[i];
        int r = atomicAdd(&cur[pkv & 255], 1);
        col[b * BCAP + r] = pkv >> 8;
    }
}

// fp8 dword-pair -> 4 floats weighted accumulate helper pieces are inlined
// via macros below (PROC1 for 8-head layer, PROC2 for 1-head layer).

// ===========================================================================
// Agg layer 1 (8 heads). Wave = 2 nodes x (8 edge-slots x 4 ch-quads).
// Each edge served by 4 lanes gathering uint4 (16B of fp8 = 16 ch = 2 heads)
// -> HALF the VMEM instructions per edge vs the 8-lane/uint2 layout (R1-R3
// showed agg time ~ # gather instructions, not bytes/cache level).
// a_src: one half2 per lane (its 2 heads); 4 lanes cover the 8-head row.
// Index prefetch 1-deep, pad-safe (col has +1024 pad).
// ===========================================================================
#define PROC1(RR, HH) { \
    float2 av = __half22float2(HH); \
    float x0 = av.x + ad2.x; x0 = x0 >= 0.f ? x0 : NEG * x0; \
    float w0 = __expf(x0); dn0 += w0; \
    float x1 = av.y + ad2.y; x1 = x1 >= 0.f ? x1 : NEG * x1; \
    float w1 = __expf(x1); dn1 += w1; \
    v2f f0 = __builtin_amdgcn_cvt_pk_f32_fp8((int)(RR).x, false); \
    v2f f1 = __builtin_amdgcn_cvt_pk_f32_fp8((int)(RR).x, true); \
    v2f f2 = __builtin_amdgcn_cvt_pk_f32_fp8((int)(RR).y, false); \
    v2f f3 = __builtin_amdgcn_cvt_pk_f32_fp8((int)(RR).y, true); \
    v2f f4 = __builtin_amdgcn_cvt_pk_f32_fp8((int)(RR).z, false); \
    v2f f5 = __builtin_amdgcn_cvt_pk_f32_fp8((int)(RR).z, true); \
    v2f f6 = __builtin_amdgcn_cvt_pk_f32_fp8((int)(RR).w, false); \
    v2f f7 = __builtin_amdgcn_cvt_pk_f32_fp8((int)(RR).w, true); \
    ac[0]  = fmaf(f0.x, w0, ac[0]);  ac[1]  = fmaf(f0.y, w0, ac[1]); \
    ac[2]  = fmaf(f1.x, w0, ac[2]);  ac[3]  = fmaf(f1.y, w0, ac[3]); \
    ac[4]  = fmaf(f2.x, w0, ac[4]);  ac[5]  = fmaf(f2.y, w0, ac[5]); \
    ac[6]  = fmaf(f3.x, w0, ac[6]);  ac[7]  = fmaf(f3.y, w0, ac[7]); \
    ac[8]  = fmaf(f4.x, w1, ac[8]);  ac[9]  = fmaf(f4.y, w1, ac[9]); \
    ac[10] = fmaf(f5.x, w1, ac[10]); ac[11] = fmaf(f5.y, w1, ac[11]); \
    ac[12] = fmaf(f6.x, w1, ac[12]); ac[13] = fmaf(f6.y, w1, ac[13]); \
    ac[14] = fmaf(f7.x, w1, ac[14]); ac[15] = fmaf(f7.y, w1, ac[15]); }

__global__ __launch_bounds__(256, 8)
void k_gat_agg1(const int* __restrict__ rbeg, const int* __restrict__ rend,
                const int* __restrict__ col,
                const __half* __restrict__ a_s, const float* __restrict__ a_d,
                const unsigned int* __restrict__ h1, const float* __restrict__ b1,
                float* __restrict__ out) {
    int wv = threadIdx.x >> 6;
    int lane = threadIdx.x & 63;
    int half = lane >> 5;
    int sl = (lane >> 2) & 7;   // edge slot (8 per node)
    int cl = lane & 3;          // ch-quad (16 ch = heads 2cl, 2cl+1)
    int d = blockIdx.x * 8 + wv * 2 + half;
    int rb = rbeg[d], re = rend[d];
    const uint4* hp = (const uint4*)h1;
    const __half2* as2 = (const __half2*)a_s;
    float2 ad2 = ((const float2*)a_d)[d * 4 + cl];
    float ac[16];
#pragma unroll
    for (int i = 0; i < 16; ++i) ac[i] = 0.f;
    float dn0 = 0.f, dn1 = 0.f;
    int ebase = rb;
    int e0 = rb + sl;
    int s0 = __builtin_nontemporal_load(col + e0);        // pad-safe
    int s1 = __builtin_nontemporal_load(col + e0 + 8);
    for (; ebase + 16 <= re; ) {
        uint4 r0 = hp[(unsigned)(s0 * 4 + cl)];
        uint4 r1 = hp[(unsigned)(s1 * 4 + cl)];
        __half2 h0 = as2[(unsigned)(s0 * 4 + cl)];
        __half2 h1v = as2[(unsigned)(s1 * 4 + cl)];
        ebase += 16; e0 += 16;
        int sn0 = __builtin_nontemporal_load(col + e0);   // speculative, pad-safe
        int sn1 = __builtin_nontemporal_load(col + e0 + 8);
        PROC1(r0, h0);
        PROC1(r1, h1v);
        s0 = sn0; s1 = sn1;
    }
    for (int et = ebase + sl; et < re; et += 8) {          // tail (<16 edges)
        int st = col[et];
        uint4 rt = hp[(unsigned)(st * 4 + cl)];
        __half2 ht = as2[(unsigned)(st * 4 + cl)];
        PROC1(rt, ht);
    }
    if (sl == 0) {      // self-loop contribution
        uint4 rs = hp[d * 4 + cl];
        __half2 hs = as2[d * 4 + cl];
        PROC1(rs, hs);
    }
#pragma unroll
    for (int i = 0; i < 16; ++i) {     // reduce over 8 slots (lane bits 2..4)
        ac[i] += __shfl_xor(ac[i], 4, 64);
        ac[i] += __shfl_xor(ac[i], 8, 64);
        ac[i] += __shfl_xor(ac[i], 16, 64);
    }
    dn0 += __shfl_xor(dn0, 4, 64); dn0 += __shfl_xor(dn0, 8, 64); dn0 += __shfl_xor(dn0, 16, 64);
    dn1 += __shfl_xor(dn1, 4, 64); dn1 += __shfl_xor(dn1, 8, 64); dn1 += __shfl_xor(dn1, 16, 64);
    if (sl == 0) {
        float inv0 = 1.0f / dn0, inv1 = 1.0f / dn1;
        const float4* b4p = (const float4*)b1;
        float4* o4 = (float4*)out;
#pragma unroll
        for (int j = 0; j < 4; ++j) {
            float4 bb = b4p[cl * 4 + j];
            float iv = (j < 2) ? inv0 : inv1;
            float4 r;
            r.x = fmaf(ac[j * 4 + 0], iv, bb.x); r.x = r.x > 0.f ? r.x : expm1f(r.x);
            r.y = fmaf(ac[j * 4 + 1], iv, bb.y); r.y = r.y > 0.f ? r.y : expm1f(r.y);
            r.z = fmaf(ac[j * 4 + 2], iv, bb.z); r.z = r.z > 0.f ? r.z : expm1f(r.z);
            r.w = fmaf(ac[j * 4 + 3], iv, bb.w); r.w = r.w > 0.f ? r.w : expm1f(r.w);
            o4[d * 16 + cl * 4 + j] = r;
        }
    }
}

// ===========================================================================
// K5: h2 = hin @ W2 (fp8 store) + a_s2/a_d2 dots. Register-tiled 8x8:
// 256 nodes/block, K=64 in 2 tiles of 32, LDS 48KB.
// ===========================================================================
__global__ __launch_bounds__(256, 3)
void k_lin2(const float* __restrict__ hin, const float* __restrict__ W2,
            const float* __restrict__ att_s, const float* __restrict__ att_d,
            unsigned int* __restrict__ h2, float* __restrict__ a_s,
            float* __restrict__ a_d) {
    __shared__ float4 sW4[D1 * 16];      // 16 KB
    __shared__ float sxT[32][256];       // 32 KB
    int tid = threadIdx.x;
    const float4* W4 = (const float4*)W2;
    for (int i = tid; i < D1 * 16; i += 256) sW4[i] = W4[i];
    int node0 = blockIdx.x * 256;
    int rg = tid >> 3, cg = tid & 7;
    float acc[8][8];
#pragma unroll
    for (int ii = 0; ii < 8; ++ii)
#pragma unroll
        for (int jj = 0; jj < 8; ++jj) acc[ii][jj] = 0.f;
    const float4* x4 = (const float4*)hin;
    for (int kt = 0; kt < 2; ++kt) {     // K tiles of 32
        if (kt) __syncthreads();
#pragma unroll
        for (int q = 0; q < 8; ++q) {    // stage 256 rows x 32 k, transposed
            int i = q * 256 + tid;
            int r = i >> 3, kc = i & 7;
            int gn = node0 + r;
            float4 v = {0.f, 0.f, 0.f, 0.f};
            if (gn < NN) v = x4[(size_t)gn * 16 + kt * 8 + kc];
            int cs = r ^ (kc << 3);
            sxT[kc * 4 + 0][cs] = v.x;
            sxT[kc * 4 + 1][cs] = v.y;
            sxT[kc * 4 + 2][cs] = v.z;
            sxT[kc * 4 + 3][cs] = v.w;
        }
        __syncthreads();
#pragma unroll 4
        for (int kk = 0; kk < 32; ++kk) {
            int sw = (kk >> 2) << 3;
            const float* xr = &sxT[kk][(rg * 8) ^ sw];
            float4 xa = *(const float4*)xr;
            float4 xb = *(const float4*)(xr + 4);
            int kg = kt * 32 + kk;
            float4 wa = sW4[kg * 16 + cg * 2];
            float4 wb = sW4[kg * 16 + cg * 2 + 1];
            float xv[8] = {xa.x, xa.y, xa.z, xa.w, xb.x, xb.y, xb.z, xb.w};
            float wv[8] = {wa.x, wa.y, wa.z, wa.w, wb.x, wb.y, wb.z, wb.w};
#pragma unroll
            for (int ii = 0; ii < 8; ++ii)
#pragma unroll
                for (int jj = 0; jj < 8; ++jj)
                    acc[ii][jj] = fmaf(xv[ii], wv[jj], acc[ii][jj]);
        }
    }
    // epilogue: fp8 pack + single-head dots (reduce over 8 cg lanes)
    float4 s0 = ((const float4*)att_s)[cg * 2];
    float4 s1 = ((const float4*)att_s)[cg * 2 + 1];
    float4 d0 = ((const float4*)att_d)[cg * 2];
    float4 d1 = ((const float4*)att_d)[cg * 2 + 1];
    uint2* hp2 = (uint2*)h2;
#pragma unroll
    for (int ii = 0; ii < 8; ++ii) {
        int n = node0 + rg * 8 + ii;
        if (n < NN) {
            float* a = acc[ii];
            int p0 = __builtin_amdgcn_cvt_pk_fp8_f32(a[0], a[1], 0, false);
            p0 = __builtin_amdgcn_cvt_pk_fp8_f32(a[2], a[3], p0, true);
            int p1 = __builtin_amdgcn_cvt_pk_fp8_f32(a[4], a[5], 0, false);
            p1 = __builtin_amdgcn_cvt_pk_fp8_f32(a[6], a[7], p1, true);
            uint2 pk; pk.x = (unsigned)p0; pk.y = (unsigned)p1;
            hp2[n * 8 + cg] = pk;
            float vs = a[0] * s0.x;
            vs = fmaf(a[1], s0.y, vs); vs = fmaf(a[2], s0.z, vs);
            vs = fmaf(a[3], s0.w, vs); vs = fmaf(a[4], s1.x, vs);
            vs = fmaf(a[5], s1.y, vs); vs = fmaf(a[6], s1.z, vs);
            vs = fmaf(a[7], s1.w, vs);
            float vd = a[0] * d0.x;
            vd = fmaf(a[1], d0.y, vd); vd = fmaf(a[2], d0.z, vd);
            vd = fmaf(a[3], d0.w, vd); vd = fmaf(a[4], d1.x, vd);
            vd = fmaf(a[5], d1.y, vd); vd = fmaf(a[6], d1.z, vd);
            vd = fmaf(a[7], d1.w, vd);
            vs += __shfl_xor(vs, 1, 64); vs += __shfl_xor(vs, 2, 64);
            vs += __shfl_xor(vs, 4, 64);
            vd += __shfl_xor(vd, 1, 64); vd += __shfl_xor(vd, 2, 64);
            vd += __shfl_xor(vd, 4, 64);
            if (cg == 0) { a_s[n] = vs; a_d[n] = vd; }
        }
    }
}

// ===========================================================================
// Agg layer 2 (1 head). Same 4-lane/edge uint4 structure; fused bias +
// mean-pool (LDS staged over 8 nodes/block; batch sorted).
// ===========================================================================
#define PROC2(RR, AV) { \
    float xx = (AV) + adv; xx = xx >= 0.f ? xx : NEG * xx; \
    float w = __expf(xx); dn += w; \
    v2f f0 = __builtin_amdgcn_cvt_pk_f32_fp8((int)(RR).x, false); \
    v2f f1 = __builtin_amdgcn_cvt_pk_f32_fp8((int)(RR).x, true); \
    v2f f2 = __builtin_amdgcn_cvt_pk_f32_fp8((int)(RR).y, false); \
    v2f f3 = __builtin_amdgcn_cvt_pk_f32_fp8((int)(RR).y, true); \
    v2f f4 = __builtin_amdgcn_cvt_pk_f32_fp8((int)(RR).z, false); \
    v2f f5 = __builtin_amdgcn_cvt_pk_f32_fp8((int)(RR).z, true); \
    v2f f6 = __builtin_amdgcn_cvt_pk_f32_fp8((int)(RR).w, false); \
    v2f f7 = __builtin_amdgcn_cvt_pk_f32_fp8((int)(RR).w, true); \
    ac[0]  = fmaf(f0.x, w, ac[0]);  ac[1]  = fmaf(f0.y, w, ac[1]); \
    ac[2]  = fmaf(f1.x, w, ac[2]);  ac[3]  = fmaf(f1.y, w, ac[3]); \
    ac[4]  = fmaf(f2.x, w, ac[4]);  ac[5]  = fmaf(f2.y, w, ac[5]); \
    ac[6]  = fmaf(f3.x, w, ac[6]);  ac[7]  = fmaf(f3.y, w, ac[7]); \
    ac[8]  = fmaf(f4.x, w, ac[8]);  ac[9]  = fmaf(f4.y, w, ac[9]); \
    ac[10] = fmaf(f5.x, w, ac[10]); ac[11] = fmaf(f5.y, w, ac[11]); \
    ac[12] = fmaf(f6.x, w, ac[12]); ac[13] = fmaf(f6.y, w, ac[13]); \
    ac[14] = fmaf(f7.x, w, ac[14]); ac[15] = fmaf(f7.y, w, ac[15]); }

__global__ __launch_bounds__(256, 8)
void k_gat_agg2(const int* __restrict__ rbeg, const int* __restrict__ rend,
                const int* __restrict__ col,
                const float* __restrict__ a_s, const float* __restrict__ a_d,
                const unsigned int* __restrict__ h2, const float* __restrict__ b2,
                const int* __restrict__ batch,
                float* __restrict__ pool, float* __restrict__ cnt) {
    __shared__ float sv[8][64];
    __shared__ int sgi[8];
    int wv = threadIdx.x >> 6;
    int lane = threadIdx.x & 63;
    int half = lane >> 5;
    int idx = wv * 2 + half;
    int d = blockIdx.x * 8 + idx;
    int sl = (lane >> 2) & 7;
    int cl = lane & 3;
    int rb = rbeg[d], re = rend[d];
    float adv = a_d[d];
    const uint4* hp = (const uint4*)h2;
    if (sl == 0 && cl == 0) sgi[idx] = batch[d];
    float ac[16];
#pragma unroll
    for (int i = 0; i < 16; ++i) ac[i] = 0.f;
    float dn = 0.f;
    int ebase = rb;
    int e0 = rb + sl;
    int s0 = __builtin_nontemporal_load(col + e0);        // pad-safe
    int s1 = __builtin_nontemporal_load(col + e0 + 8);
    for (; ebase + 16 <= re; ) {
        uint4 r0 = hp[(unsigned)(s0 * 4 + cl)];
        uint4 r1 = hp[(unsigned)(s1 * 4 + cl)];
        float a0 = a_s[(unsigned)s0];
        float a1 = a_s[(unsigned)s1];
        ebase += 16; e0 += 16;
        int sn0 = __builtin_nontemporal_load(col + e0);   // speculative, pad-safe
        int sn1 = __builtin_nontemporal_load(col + e0 + 8);
        PROC2(r0, a0);
        PROC2(r1, a1);
        s0 = sn0; s1 = sn1;
    }
    for (int et = ebase + sl; et < re; et += 8) {          // tail
        int st = col[et];
        uint4 rt = hp[(unsigned)(st * 4 + cl)];
        float at = a_s[(unsigned)st];
        PROC2(rt, at);
    }
    if (sl == 0) {      // self-loop
        uint4 rs = hp[d * 4 + cl];
        float asf = a_s[d];
        PROC2(rs, asf);
    }
#pragma unroll
    for (int i = 0; i < 16; ++i) {
        ac[i] += __shfl_xor(ac[i], 4, 64);
        ac[i] += __shfl_xor(ac[i], 8, 64);
        ac[i] += __shfl_xor(ac[i], 16, 64);
    }
    dn += __shfl_xor(dn, 4, 64); dn += __shfl_xor(dn, 8, 64); dn += __shfl_xor(dn, 16, 64);
    if (sl == 0) {
        float inv = 1.0f / dn;
#pragma unroll
        for (int i = 0; i < 16; ++i)
            sv[idx][cl * 16 + i] = fmaf(ac[i], inv, b2[cl * 16 + i]);
    }
    __syncthreads();
    int tid = threadIdx.x;
    if (tid < 64) {
        float acc = sv[0][tid]; int curg = sgi[0];
        for (int r = 1; r < 8; ++r) {
            if (sgi[r] == curg) acc += sv[r][tid];
            else { atomicAdd(&pool[curg * 64 + tid], acc); curg = sgi[r]; acc = sv[r][tid]; }
        }
        atomicAdd(&pool[curg * 64 + tid], acc);
    } else if (tid == 64) {
        float c = 1.f; int curg = sgi[0];
        for (int r = 1; r < 8; ++r) {
            if (sgi[r] == curg) c += 1.f;
            else { atomicAdd(&cnt[curg], c); curg = sgi[r]; c = 1.f; }
        }
        atomicAdd(&cnt[curg], c);
    }
}

// K9: g = pool/cnt ; hidden = elu(g@lw1+lb1) ; out = hidden@lw2 + lb2
__global__ __launch_bounds__(128)
void k_mlp(const float* __restrict__ pool, const float* __restrict__ cnt,
           const float* __restrict__ lw1, const float* __restrict__ lb1,
           const float* __restrict__ lw2, const float* __restrict__ lb2,
           float* __restrict__ out) {
    __shared__ float sg[OUTC];
    __shared__ float sh[HID];
    int g = blockIdx.x, tid = threadIdx.x;
    float c = fmaxf(cnt[g], 1.0f);
    if (tid < OUTC) sg[tid] = pool[g * OUTC + tid] / c;
    __syncthreads();
    float acc = lb1[tid];
#pragma unroll 8
    for (int k = 0; k < OUTC; ++k)
        acc = fmaf(sg[k], lw1[k * HID + tid], acc);
    acc = acc > 0.f ? acc : expm1f(acc);
    sh[tid] = acc * lw2[tid];
    __syncthreads();
    for (int off = 64; off >= 1; off >>= 1) {
        if (tid < off) sh[tid] += sh[tid + off];
        __syncthreads();
    }
    if (tid == 0) out[g] = sh[0] + lb2[0];
}

extern "C" void kernel_launch(void* const* d_in, const int* in_sizes, int n_in,
                              void* d_out, int out_size, void* d_ws, size_t ws_size,
                              hipStream_t stream) {
    const float* x    = (const float*)d_in[0];
    const int*   ei   = (const int*)d_in[1];
    const int*   batch= (const int*)d_in[2];
    const float* W1   = (const float*)d_in[3];
    const float* as1  = (const float*)d_in[4];
    const float* ad1  = (const float*)d_in[5];
    const float* b1   = (const float*)d_in[6];
    const float* W2   = (const float*)d_in[7];
    const float* as2  = (const float*)d_in[8];
    const float* ad2  = (const float*)d_in[9];
    const float* b2   = (const float*)d_in[10];
    const float* lw1  = (const float*)d_in[11];
    const float* lb1  = (const float*)d_in[12];
    const float* lw2  = (const float*)d_in[13];
    const float* lb2  = (const float*)d_in[14];
    float* out = (float*)d_out;

    // workspace layout (~67 MB); colv has +1024-int pad for pipelined preloads
    unsigned int* H8 = (unsigned int*)d_ws;          // N*16 uints = fp8 table (6.4 MB)
    float* B    = (float*)(H8 + (size_t)NN * 16);    // N*64 fp32 (25.6 MB)
    float* aD1  = B + (size_t)NN * 64;               // N*8
    float* aS2  = aD1 + NN * 8;                      // N
    float* aD2  = aS2 + NN;                          // N
    float* pool = aD2 + NN;                          // G*64
    float* cnt  = pool + GG * 64;                    // G
    __half* aS1h = (__half*)(cnt + GG);              // N*8 fp16 (1.6 MB)
    int* rbeg   = (int*)(aS1h + (size_t)NN * 8);     // N
    int* rend   = rbeg + NN;                         // N
    int* cursor = rend + NN;                         // BINS
    int* bucket = cursor + BINS;                     // BINS*BCAP (14.4 MB)
    int* colv   = bucket + (size_t)BINS * BCAP;      // BINS*BCAP + pad

    const int* srcv = ei;
    const int* dstv = ei + EE;

    hipMemsetAsync(cursor, 0, BINS * sizeof(int), stream);
    hipMemsetAsync(pool, 0, (size_t)(GG * 64 + GG) * sizeof(float), stream);

    // FUSED: lin1 GEMM (391 long blocks, first) + bucket scatter (1563 short)
    k_fused<<<NGB + BKBLK, 256, 0, stream>>>(srcv, dstv, cursor, bucket,
                                             x, W1, as1, ad1, H8, aS1h, aD1);
    k_binCSR<<<BINS, 256, 0, stream>>>(cursor, bucket, colv, rbeg, rend);

    // layer 1 aggregation
    k_gat_agg1<<<NN / 8, 256, 0, stream>>>(rbeg, rend, colv, aS1h, aD1, H8, b1, B);

    // layer 2 (agg fused with bias + mean-pool accumulation)
    k_lin2    <<<NGB, 256, 0, stream>>>(B, W2, as2, ad2, H8, aS2, aD2);
    k_gat_agg2<<<NN / 8, 256, 0, stream>>>(rbeg, rend, colv, aS2, aD2, H8, b2, batch, pool, cnt);

    // MLP head
    k_mlp<<<GG, 128, 0, stream>>>(pool, cnt, lw1, lb1, lw2, lb2, out);
}

// Round 6
// 350.776 us; speedup vs baseline: 1.1152x; 1.1152x over previous
//
#include <hip/hip_runtime.h>
#include <hip/hip_fp16.h>
#include <math.h>

// Problem constants (match reference)
#define NN   100000
#define EE   3200000
#define GG   512
#define INC  128
#define D1   64        // H1*C1 = 8*8
#define OUTC 64
#define HID  128
#define NEG  0.2f

// Two-level CSR binning: 128-node bins (782 blocks -> 3/CU in k_binCSR)
#define BINS   782     // ceil(NN/128)
#define BNODE  128
#define BSHIFT 7
#define BMASK  127
#define BCAP   4800    // Binomial mean 4096 + 11 sigma; overflow-guarded
#define BKBLK 1563     // ceil(EE/2048) bucket blocks in the fused kernel
#define NGB 391        // ceil(NN/256) register-tiled GEMM blocks

typedef __attribute__((ext_vector_type(2))) float v2f;

// Node record layout (both layers, shared buffer REC, 128B/node aligned):
//   bytes  0..63 : 64 x fp8 h-row
//   bytes 64..79 : layer1: 8 x half a_src   | layer2: float a_src at byte 64
//   bytes 80..127: pad
// One 128B line per edge-gather: the a_src read lands in the SAME line as
// the h gather -> second L1 request per edge becomes a line hit.

// ===========================================================================
// FUSED: [blocks 0..NGB) = lin1 GEMM (long blocks, launched first)
//        [NGB..NGB+BKBLK) = bucket scatter (short, fills remaining slots).
// lin1 is a register-tiled 8x8 GEMM: 256 nodes/block, thread = 8 rows x 8
// cols, per-k LDS = 4x ds_read_b128 for 64 FMAs.
// ===========================================================================
__global__ __launch_bounds__(256, 3)
void k_fused(const int* __restrict__ srcv, const int* __restrict__ dstv,
             int* __restrict__ cursor, int* __restrict__ bucket,
             const float* __restrict__ x, const float* __restrict__ W1,
             const float* __restrict__ att_s, const float* __restrict__ att_d,
             unsigned int* __restrict__ rec, float* __restrict__ a_d) {
    __shared__ __align__(16) char smem[49152];
    int tid = threadIdx.x;
    if (blockIdx.x < NGB) {
        // ---------------- lin1: rec = x @ W1 (fp8 + a_s), attention dots ---
        float4* sW4 = (float4*)smem;                        // 32768 B
        float (*sxT)[256] = (float(*)[256])(smem + 32768);  // 16x256x4 = 16384 B
        const float4* W4 = (const float4*)W1;
        for (int i = tid; i < 128 * 16; i += 256) sW4[i] = W4[i];
        int node0 = blockIdx.x * 256;
        int rg = tid >> 3, cg = tid & 7;     // 32 row-groups x 8 col-groups
        float acc[8][8];
#pragma unroll
        for (int ii = 0; ii < 8; ++ii)
#pragma unroll
            for (int jj = 0; jj < 8; ++jj) acc[ii][jj] = 0.f;
        const float4* x4 = (const float4*)x;
        for (int kt = 0; kt < 8; ++kt) {     // K tiles of 16
            if (kt) __syncthreads();         // readers done with prev tile
#pragma unroll
            for (int q = 0; q < 4; ++q) {    // stage 256 rows x 16 k, transposed
                int i = q * 256 + tid;
                int r = i >> 2, kc = i & 3;
                int gn = node0 + r;
                float4 v = {0.f, 0.f, 0.f, 0.f};
                if (gn < NN) v = x4[(size_t)gn * 32 + kt * 4 + kc];
                int cs = r ^ (kc << 3);      // swizzle: s = (k>>2)<<3, k>>2 = kc
                sxT[kc * 4 + 0][cs] = v.x;
                sxT[kc * 4 + 1][cs] = v.y;
                sxT[kc * 4 + 2][cs] = v.z;
                sxT[kc * 4 + 3][cs] = v.w;
            }
            __syncthreads();
#pragma unroll 4
            for (int kk = 0; kk < 16; ++kk) {
                int sw = (kk >> 2) << 3;
                const float* xr = &sxT[kk][(rg * 8) ^ sw];
                float4 xa = *(const float4*)xr;
                float4 xb = *(const float4*)(xr + 4);
                int kg = kt * 16 + kk;
                float4 wa = sW4[kg * 16 + cg * 2];
                float4 wb = sW4[kg * 16 + cg * 2 + 1];
                float xv[8] = {xa.x, xa.y, xa.z, xa.w, xb.x, xb.y, xb.z, xb.w};
                float wv[8] = {wa.x, wa.y, wa.z, wa.w, wb.x, wb.y, wb.z, wb.w};
#pragma unroll
                for (int ii = 0; ii < 8; ++ii)
#pragma unroll
                    for (int jj = 0; jj < 8; ++jj)
                        acc[ii][jj] = fmaf(xv[ii], wv[jj], acc[ii][jj]);
            }
        }
        // epilogue: fp8 pack + per-head attention dots (head == cg, no reduce)
        float4 s0 = ((const float4*)att_s)[cg * 2];
        float4 s1 = ((const float4*)att_s)[cg * 2 + 1];
        float4 d0 = ((const float4*)att_d)[cg * 2];
        float4 d1 = ((const float4*)att_d)[cg * 2 + 1];
        uint2* hp2 = (uint2*)rec;
        __half* ash = (__half*)rec;
#pragma unroll
        for (int ii = 0; ii < 8; ++ii) {
            int n = node0 + rg * 8 + ii;
            if (n < NN) {
                float* a = acc[ii];
                int p0 = __builtin_amdgcn_cvt_pk_fp8_f32(a[0], a[1], 0, false);
                p0 = __builtin_amdgcn_cvt_pk_fp8_f32(a[2], a[3], p0, true);
                int p1 = __builtin_amdgcn_cvt_pk_fp8_f32(a[4], a[5], 0, false);
                p1 = __builtin_amdgcn_cvt_pk_fp8_f32(a[6], a[7], p1, true);
                uint2 pk; pk.x = (unsigned)p0; pk.y = (unsigned)p1;
                hp2[n * 16 + cg] = pk;       // record stride 128B = 16 uint2
                float as = a[0] * s0.x;
                as = fmaf(a[1], s0.y, as); as = fmaf(a[2], s0.z, as);
                as = fmaf(a[3], s0.w, as); as = fmaf(a[4], s1.x, as);
                as = fmaf(a[5], s1.y, as); as = fmaf(a[6], s1.z, as);
                as = fmaf(a[7], s1.w, as);
                float ad = a[0] * d0.x;
                ad = fmaf(a[1], d0.y, ad); ad = fmaf(a[2], d0.z, ad);
                ad = fmaf(a[3], d0.w, ad); ad = fmaf(a[4], d1.x, ad);
                ad = fmaf(a[5], d1.y, ad); ad = fmaf(a[6], d1.z, ad);
                ad = fmaf(a[7], d1.w, ad);
                ash[n * 64 + 32 + cg] = __float2half(as);   // byte 64 + 2*cg
                a_d[n * 8 + cg] = ad;
            }
        }
    } else {
        // ---------------- bucket scatter (128-node bins) ----------------
        int* hcnt  = (int*)smem;          // BINS
        int* hbase = hcnt + BINS;         // BINS
        for (int i = tid; i < BINS; i += 256) hcnt[i] = 0;
        __syncthreads();
        int e0 = (blockIdx.x - NGB) * 2048;
        int bn[8], rk[8], pk[8];
#pragma unroll
        for (int q = 0; q < 8; ++q) {
            int e = e0 + q * 256 + tid;
            if (e < EE) {
                int s = srcv[e], d = dstv[e];
                bn[q] = d >> BSHIFT;
                pk[q] = (s << BSHIFT) | (d & BMASK);
                rk[q] = atomicAdd(&hcnt[bn[q]], 1);   // LDS atomic
            } else bn[q] = -1;
        }
        __syncthreads();
        for (int i = tid; i < BINS; i += 256) {
            int c = hcnt[i];
            hbase[i] = c ? atomicAdd(&cursor[i], c) : 0;
        }
        __syncthreads();
#pragma unroll
        for (int q = 0; q < 8; ++q) {
            if (bn[q] >= 0) {
                int p = hbase[bn[q]] + rk[q];
                if (p < BCAP) bucket[bn[q] * BCAP + p] = pk[q];
            }
        }
    }
}

// ===========================================================================
// P3: per-bin fine CSR. One block per 128-node bin (782 blocks -> 3/CU, 2x
// the old occupancy). Two streaming passes over the bin segment (in L2).
// ===========================================================================
__global__ __launch_bounds__(256)
void k_binCSR(const int* __restrict__ cursor, const int* __restrict__ bucket,
              int* __restrict__ col, int* __restrict__ rbeg, int* __restrict__ rend) {
    __shared__ int cnt_[BNODE];
    __shared__ int tmp[BNODE];
    __shared__ int cur[BNODE];
    int b = blockIdx.x, tid = threadIdx.x;
    if (tid < BNODE) cnt_[tid] = 0;
    __syncthreads();
    int m = cursor[b]; if (m > BCAP) m = BCAP;
    const int* seg = bucket + b * BCAP;
    for (int i = tid; i < m; i += 256)
        atomicAdd(&cnt_[seg[i] & BMASK], 1);
    __syncthreads();
    if (tid < BNODE) tmp[tid] = cnt_[tid];
    __syncthreads();
    for (int off = 1; off < BNODE; off <<= 1) {
        int t = (tid >= off && tid < BNODE) ? tmp[tid - off] : 0;
        __syncthreads();
        if (tid < BNODE) tmp[tid] += t;
        __syncthreads();
    }
    if (tid < BNODE) {
        int excl = tmp[tid] - cnt_[tid];
        int n = b * BNODE + tid;
        if (n < NN) {
            rbeg[n] = b * BCAP + excl;
            rend[n] = b * BCAP + excl + cnt_[tid];
        }
        cur[tid] = excl;
    }
    __syncthreads();
    for (int i = tid; i < m; i += 256) {
        int pkv = seg[i];
        int r = atomicAdd(&cur[pkv & BMASK], 1);
        col[b * BCAP + r] = pkv >> BSHIFT;
    }
}

// ===========================================================================
// Agg layer 1 (8 heads). Wave = 2 nodes x (4 edge-slots x 8 lanes), lane&7 =
// head = ch-group (uint2 fp8 row slice). 1-deep index prefetch (pad-safe).
// a_src read from the SAME 128B record line as the h gather.
// ===========================================================================
__global__ __launch_bounds__(256, 8)
void k_gat_agg1(const int* __restrict__ rbeg, const int* __restrict__ rend,
                const int* __restrict__ col,
                const unsigned int* __restrict__ rec, const float* __restrict__ a_d,
                const float* __restrict__ b1, float* __restrict__ out) {
    int wv = threadIdx.x >> 6;
    int lane = threadIdx.x & 63;
    int half = lane >> 5;
    int d = blockIdx.x * 8 + wv * 2 + half;
    int gs = (lane >> 3) & 3;   // slot within node
    int l = lane & 7;           // head / ch-group
    int rb = rbeg[d], re = rend[d];
    float adh = a_d[d * 8 + l];
    const uint2* hp = (const uint2*)rec;
    const __half* asr = (const __half*)rec;
    uint2 rself = hp[d * 16 + l];
    float asself = __half2float(asr[d * 64 + 32 + l]);
    float ac[8] = {0.f,0.f,0.f,0.f,0.f,0.f,0.f,0.f};
    float denom = 0.f;
    int e = rb + gs;
    int s[4];
#pragma unroll
    for (int q = 0; q < 4; ++q) s[q] = col[e + 4 * q];   // pad-safe preload
    for (; e + 12 < re; ) {
        uint2 rr[4]; float asv[4]; int sn[4];
#pragma unroll
        for (int q = 0; q < 4; ++q) rr[q] = hp[(unsigned)(s[q] * 16 + l)];
#pragma unroll
        for (int q = 0; q < 4; ++q) asv[q] = __half2float(asr[(unsigned)(s[q] * 64 + 32 + l)]);
        int en = e + 16;
#pragma unroll
        for (int q = 0; q < 4; ++q) sn[q] = col[en + 4 * q];  // prefetch next
#pragma unroll
        for (int q = 0; q < 4; ++q) {
            float xx = asv[q] + adh;
            xx = xx >= 0.f ? xx : NEG * xx;
            float w = __expf(xx);
            denom += w;
            v2f f0 = __builtin_amdgcn_cvt_pk_f32_fp8((int)rr[q].x, false);
            v2f f1 = __builtin_amdgcn_cvt_pk_f32_fp8((int)rr[q].x, true);
            v2f f2 = __builtin_amdgcn_cvt_pk_f32_fp8((int)rr[q].y, false);
            v2f f3 = __builtin_amdgcn_cvt_pk_f32_fp8((int)rr[q].y, true);
            ac[0] = fmaf(f0.x, w, ac[0]); ac[1] = fmaf(f0.y, w, ac[1]);
            ac[2] = fmaf(f1.x, w, ac[2]); ac[3] = fmaf(f1.y, w, ac[3]);
            ac[4] = fmaf(f2.x, w, ac[4]); ac[5] = fmaf(f2.y, w, ac[5]);
            ac[6] = fmaf(f3.x, w, ac[6]); ac[7] = fmaf(f3.y, w, ac[7]);
        }
        e = en;
#pragma unroll
        for (int q = 0; q < 4; ++q) s[q] = sn[q];
    }
    for (; e < re; e += 4) {
        int s0 = col[e];
        uint2 r0 = hp[(unsigned)(s0 * 16 + l)];
        float x0 = __half2float(asr[(unsigned)(s0 * 64 + 32 + l)]) + adh;
        x0 = x0 >= 0.f ? x0 : NEG * x0;
        float w0 = __expf(x0);
        denom += w0;
        v2f f0 = __builtin_amdgcn_cvt_pk_f32_fp8((int)r0.x, false);
        v2f f1 = __builtin_amdgcn_cvt_pk_f32_fp8((int)r0.x, true);
        v2f f2 = __builtin_amdgcn_cvt_pk_f32_fp8((int)r0.y, false);
        v2f f3 = __builtin_amdgcn_cvt_pk_f32_fp8((int)r0.y, true);
        ac[0] = fmaf(f0.x, w0, ac[0]); ac[1] = fmaf(f0.y, w0, ac[1]);
        ac[2] = fmaf(f1.x, w0, ac[2]); ac[3] = fmaf(f1.y, w0, ac[3]);
        ac[4] = fmaf(f2.x, w0, ac[4]); ac[5] = fmaf(f2.y, w0, ac[5]);
        ac[6] = fmaf(f3.x, w0, ac[6]); ac[7] = fmaf(f3.y, w0, ac[7]);
    }
    if (gs == 0) {      // self-loop contribution
        float es = asself + adh;
        es = es >= 0.f ? es : NEG * es;
        float w = __expf(es);
        denom += w;
        v2f f0 = __builtin_amdgcn_cvt_pk_f32_fp8((int)rself.x, false);
        v2f f1 = __builtin_amdgcn_cvt_pk_f32_fp8((int)rself.x, true);
        v2f f2 = __builtin_amdgcn_cvt_pk_f32_fp8((int)rself.y, false);
        v2f f3 = __builtin_amdgcn_cvt_pk_f32_fp8((int)rself.y, true);
        ac[0] = fmaf(f0.x, w, ac[0]); ac[1] = fmaf(f0.y, w, ac[1]);
        ac[2] = fmaf(f1.x, w, ac[2]); ac[3] = fmaf(f1.y, w, ac[3]);
        ac[4] = fmaf(f2.x, w, ac[4]); ac[5] = fmaf(f2.y, w, ac[5]);
        ac[6] = fmaf(f3.x, w, ac[6]); ac[7] = fmaf(f3.y, w, ac[7]);
    }
#pragma unroll
    for (int i = 0; i < 8; ++i) {     // reduce 4 slots (stays within 32-half)
        ac[i] += __shfl_xor(ac[i], 8, 64);
        ac[i] += __shfl_xor(ac[i], 16, 64);
    }
    denom += __shfl_xor(denom, 8, 64);
    denom += __shfl_xor(denom, 16, 64);
    if (gs == 0) {
        float inv = 1.0f / denom;
        float4 b0 = ((const float4*)b1)[l * 2];
        float4 b4 = ((const float4*)b1)[l * 2 + 1];
        float4 r0, r1;
        r0.x = fmaf(ac[0], inv, b0.x); r0.x = r0.x > 0.f ? r0.x : expm1f(r0.x);
        r0.y = fmaf(ac[1], inv, b0.y); r0.y = r0.y > 0.f ? r0.y : expm1f(r0.y);
        r0.z = fmaf(ac[2], inv, b0.z); r0.z = r0.z > 0.f ? r0.z : expm1f(r0.z);
        r0.w = fmaf(ac[3], inv, b0.w); r0.w = r0.w > 0.f ? r0.w : expm1f(r0.w);
        r1.x = fmaf(ac[4], inv, b4.x); r1.x = r1.x > 0.f ? r1.x : expm1f(r1.x);
        r1.y = fmaf(ac[5], inv, b4.y); r1.y = r1.y > 0.f ? r1.y : expm1f(r1.y);
        r1.z = fmaf(ac[6], inv, b4.z); r1.z = r1.z > 0.f ? r1.z : expm1f(r1.z);
        r1.w = fmaf(ac[7], inv, b4.w); r1.w = r1.w > 0.f ? r1.w : expm1f(r1.w);
        ((float4*)out)[d * 16 + l * 2]     = r0;
        ((float4*)out)[d * 16 + l * 2 + 1] = r1;
    }
}

// ===========================================================================
// K5: rec = hin @ W2 (fp8 + a_s2 in 128B records) + a_d2. Register-tiled
// 8x8: 256 nodes/block, K=64 in 2 tiles of 32, LDS 48KB. Overwrites the
// layer-1 records (agg1 already complete; stream-ordered).
// ===========================================================================
__global__ __launch_bounds__(256, 3)
void k_lin2(const float* __restrict__ hin, const float* __restrict__ W2,
            const float* __restrict__ att_s, const float* __restrict__ att_d,
            unsigned int* __restrict__ rec, float* __restrict__ a_d) {
    __shared__ float4 sW4[D1 * 16];      // 16 KB
    __shared__ float sxT[32][256];       // 32 KB
    int tid = threadIdx.x;
    const float4* W4 = (const float4*)W2;
    for (int i = tid; i < D1 * 16; i += 256) sW4[i] = W4[i];
    int node0 = blockIdx.x * 256;
    int rg = tid >> 3, cg = tid & 7;
    float acc[8][8];
#pragma unroll
    for (int ii = 0; ii < 8; ++ii)
#pragma unroll
        for (int jj = 0; jj < 8; ++jj) acc[ii][jj] = 0.f;
    const float4* x4 = (const float4*)hin;
    for (int kt = 0; kt < 2; ++kt) {     // K tiles of 32
        if (kt) __syncthreads();
#pragma unroll
        for (int q = 0; q < 8; ++q) {    // stage 256 rows x 32 k, transposed
            int i = q * 256 + tid;
            int r = i >> 3, kc = i & 7;
            int gn = node0 + r;
            float4 v = {0.f, 0.f, 0.f, 0.f};
            if (gn < NN) v = x4[(size_t)gn * 16 + kt * 8 + kc];
            int cs = r ^ (kc << 3);
            sxT[kc * 4 + 0][cs] = v.x;
            sxT[kc * 4 + 1][cs] = v.y;
            sxT[kc * 4 + 2][cs] = v.z;
            sxT[kc * 4 + 3][cs] = v.w;
        }
        __syncthreads();
#pragma unroll 4
        for (int kk = 0; kk < 32; ++kk) {
            int sw = (kk >> 2) << 3;
            const float* xr = &sxT[kk][(rg * 8) ^ sw];
            float4 xa = *(const float4*)xr;
            float4 xb = *(const float4*)(xr + 4);
            int kg = kt * 32 + kk;
            float4 wa = sW4[kg * 16 + cg * 2];
            float4 wb = sW4[kg * 16 + cg * 2 + 1];
            float xv[8] = {xa.x, xa.y, xa.z, xa.w, xb.x, xb.y, xb.z, xb.w};
            float wv[8] = {wa.x, wa.y, wa.z, wa.w, wb.x, wb.y, wb.z, wb.w};
#pragma unroll
            for (int ii = 0; ii < 8; ++ii)
#pragma unroll
                for (int jj = 0; jj < 8; ++jj)
                    acc[ii][jj] = fmaf(xv[ii], wv[jj], acc[ii][jj]);
        }
    }
    // epilogue: fp8 pack + single-head dots (reduce over 8 cg lanes)
    float4 s0 = ((const float4*)att_s)[cg * 2];
    float4 s1 = ((const float4*)att_s)[cg * 2 + 1];
    float4 d0 = ((const float4*)att_d)[cg * 2];
    float4 d1 = ((const float4*)att_d)[cg * 2 + 1];
    uint2* hp2 = (uint2*)rec;
#pragma unroll
    for (int ii = 0; ii < 8; ++ii) {
        int n = node0 + rg * 8 + ii;
        if (n < NN) {
            float* a = acc[ii];
            int p0 = __builtin_amdgcn_cvt_pk_fp8_f32(a[0], a[1], 0, false);
            p0 = __builtin_amdgcn_cvt_pk_fp8_f32(a[2], a[3], p0, true);
            int p1 = __builtin_amdgcn_cvt_pk_fp8_f32(a[4], a[5], 0, false);
            p1 = __builtin_amdgcn_cvt_pk_fp8_f32(a[6], a[7], p1, true);
            uint2 pk; pk.x = (unsigned)p0; pk.y = (unsigned)p1;
            hp2[n * 16 + cg] = pk;
            float vs = a[0] * s0.x;
            vs = fmaf(a[1], s0.y, vs); vs = fmaf(a[2], s0.z, vs);
            vs = fmaf(a[3], s0.w, vs); vs = fmaf(a[4], s1.x, vs);
            vs = fmaf(a[5], s1.y, vs); vs = fmaf(a[6], s1.z, vs);
            vs = fmaf(a[7], s1.w, vs);
            float vd = a[0] * d0.x;
            vd = fmaf(a[1], d0.y, vd); vd = fmaf(a[2], d0.z, vd);
            vd = fmaf(a[3], d0.w, vd); vd = fmaf(a[4], d1.x, vd);
            vd = fmaf(a[5], d1.y, vd); vd = fmaf(a[6], d1.z, vd);
            vd = fmaf(a[7], d1.w, vd);
            vs += __shfl_xor(vs, 1, 64); vs += __shfl_xor(vs, 2, 64);
            vs += __shfl_xor(vs, 4, 64);
            vd += __shfl_xor(vd, 1, 64); vd += __shfl_xor(vd, 2, 64);
            vd += __shfl_xor(vd, 4, 64);
            if (cg == 0) {
                ((float*)rec)[(size_t)n * 32 + 16] = vs;   // byte offset 64
                a_d[n] = vd;
            }
        }
    }
}

// ===========================================================================
// Agg layer 2 (1 head). Same 2-node/wave pipelined structure; a_s2 read
// from the same 128B record line as the h gather. Fused bias + mean-pool.
// ===========================================================================
__global__ __launch_bounds__(256, 8)
void k_gat_agg2(const int* __restrict__ rbeg, const int* __restrict__ rend,
                const int* __restrict__ col,
                const unsigned int* __restrict__ rec, const float* __restrict__ a_d,
                const float* __restrict__ b2, const int* __restrict__ batch,
                float* __restrict__ pool, float* __restrict__ cnt) {
    __shared__ float sv[8][64];
    __shared__ int sgi[8];
    int wv = threadIdx.x >> 6;
    int lane = threadIdx.x & 63;
    int half = lane >> 5;
    int idx = wv * 2 + half;
    int d = blockIdx.x * 8 + idx;
    int gs = (lane >> 3) & 3;
    int l = lane & 7;
    int rb = rbeg[d], re = rend[d];
    float ad = a_d[d];
    const uint2* hp = (const uint2*)rec;
    const float* recf = (const float*)rec;
    uint2 rself = hp[d * 16 + l];
    float asself = recf[d * 32 + 16];
    if (gs == 0 && l == 0) sgi[idx] = batch[d];
    float ac[8] = {0.f,0.f,0.f,0.f,0.f,0.f,0.f,0.f};
    float denom = 0.f;
    int e = rb + gs;
    int s[4];
#pragma unroll
    for (int q = 0; q < 4; ++q) s[q] = col[e + 4 * q];
    for (; e + 12 < re; ) {
        uint2 rr[4]; float asv[4]; int sn[4];
#pragma unroll
        for (int q = 0; q < 4; ++q) rr[q] = hp[(unsigned)(s[q] * 16 + l)];
#pragma unroll
        for (int q = 0; q < 4; ++q) asv[q] = recf[(unsigned)(s[q] * 32 + 16)];
        int en = e + 16;
#pragma unroll
        for (int q = 0; q < 4; ++q) sn[q] = col[en + 4 * q];
#pragma unroll
        for (int q = 0; q < 4; ++q) {
            float xx = asv[q] + ad;
            xx = xx >= 0.f ? xx : NEG * xx;
            float w = __expf(xx);
            denom += w;
            v2f f0 = __builtin_amdgcn_cvt_pk_f32_fp8((int)rr[q].x, false);
            v2f f1 = __builtin_amdgcn_cvt_pk_f32_fp8((int)rr[q].x, true);
            v2f f2 = __builtin_amdgcn_cvt_pk_f32_fp8((int)rr[q].y, false);
            v2f f3 = __builtin_amdgcn_cvt_pk_f32_fp8((int)rr[q].y, true);
            ac[0] = fmaf(f0.x, w, ac[0]); ac[1] = fmaf(f0.y, w, ac[1]);
            ac[2] = fmaf(f1.x, w, ac[2]); ac[3] = fmaf(f1.y, w, ac[3]);
            ac[4] = fmaf(f2.x, w, ac[4]); ac[5] = fmaf(f2.y, w, ac[5]);
            ac[6] = fmaf(f3.x, w, ac[6]); ac[7] = fmaf(f3.y, w, ac[7]);
        }
        e = en;
#pragma unroll
        for (int q = 0; q < 4; ++q) s[q] = sn[q];
    }
    for (; e < re; e += 4) {
        int s0 = col[e];
        uint2 r0 = hp[(unsigned)(s0 * 16 + l)];
        float x0 = recf[(unsigned)(s0 * 32 + 16)] + ad;
        x0 = x0 >= 0.f ? x0 : NEG * x0;
        float w0 = __expf(x0);
        denom += w0;
        v2f f0 = __builtin_amdgcn_cvt_pk_f32_fp8((int)r0.x, false);
        v2f f1 = __builtin_amdgcn_cvt_pk_f32_fp8((int)r0.x, true);
        v2f f2 = __builtin_amdgcn_cvt_pk_f32_fp8((int)r0.y, false);
        v2f f3 = __builtin_amdgcn_cvt_pk_f32_fp8((int)r0.y, true);
        ac[0] = fmaf(f0.x, w0, ac[0]); ac[1] = fmaf(f0.y, w0, ac[1]);
        ac[2] = fmaf(f1.x, w0, ac[2]); ac[3] = fmaf(f1.y, w0, ac[3]);
        ac[4] = fmaf(f2.x, w0, ac[4]); ac[5] = fmaf(f2.y, w0, ac[5]);
        ac[6] = fmaf(f3.x, w0, ac[6]); ac[7] = fmaf(f3.y, w0, ac[7]);
    }
    if (gs == 0) {
        float es = asself + ad;
        es = es >= 0.f ? es : NEG * es;
        float w = __expf(es);
        denom += w;
        v2f f0 = __builtin_amdgcn_cvt_pk_f32_fp8((int)rself.x, false);
        v2f f1 = __builtin_amdgcn_cvt_pk_f32_fp8((int)rself.x, true);
        v2f f2 = __builtin_amdgcn_cvt_pk_f32_fp8((int)rself.y, false);
        v2f f3 = __builtin_amdgcn_cvt_pk_f32_fp8((int)rself.y, true);
        ac[0] = fmaf(f0.x, w, ac[0]); ac[1] = fmaf(f0.y, w, ac[1]);
        ac[2] = fmaf(f1.x, w, ac[2]); ac[3] = fmaf(f1.y, w, ac[3]);
        ac[4] = fmaf(f2.x, w, ac[4]); ac[5] = fmaf(f2.y, w, ac[5]);
        ac[6] = fmaf(f3.x, w, ac[6]); ac[7] = fmaf(f3.y, w, ac[7]);
    }
#pragma unroll
    for (int i = 0; i < 8; ++i) {
        ac[i] += __shfl_xor(ac[i], 8, 64);
        ac[i] += __shfl_xor(ac[i], 16, 64);
    }
    denom += __shfl_xor(denom, 8, 64);
    denom += __shfl_xor(denom, 16, 64);
    if (gs == 0) {
        float inv = 1.0f / denom;
#pragma unroll
        for (int i = 0; i < 8; ++i)
            sv[idx][l * 8 + i] = fmaf(ac[i], inv, b2[l * 8 + i]);
    }
    __syncthreads();
    int tid = threadIdx.x;
    if (tid < 64) {
        float acc = sv[0][tid]; int curg = sgi[0];
        for (int r = 1; r < 8; ++r) {
            if (sgi[r] == curg) acc += sv[r][tid];
            else { atomicAdd(&pool[curg * 64 + tid], acc); curg = sgi[r]; acc = sv[r][tid]; }
        }
        atomicAdd(&pool[curg * 64 + tid], acc);
    } else if (tid == 64) {
        float c = 1.f; int curg = sgi[0];
        for (int r = 1; r < 8; ++r) {
            if (sgi[r] == curg) c += 1.f;
            else { atomicAdd(&cnt[curg], c); curg = sgi[r]; c = 1.f; }
        }
        atomicAdd(&cnt[curg], c);
    }
}

// K9: g = pool/cnt ; hidden = elu(g@lw1+lb1) ; out = hidden@lw2 + lb2
__global__ __launch_bounds__(128)
void k_mlp(const float* __restrict__ pool, const float* __restrict__ cnt,
           const float* __restrict__ lw1, const float* __restrict__ lb1,
           const float* __restrict__ lw2, const float* __restrict__ lb2,
           float* __restrict__ out) {
    __shared__ float sg[OUTC];
    __shared__ float sh[HID];
    int g = blockIdx.x, tid = threadIdx.x;
    float c = fmaxf(cnt[g], 1.0f);
    if (tid < OUTC) sg[tid] = pool[g * OUTC + tid] / c;
    __syncthreads();
    float acc = lb1[tid];
#pragma unroll 8
    for (int k = 0; k < OUTC; ++k)
        acc = fmaf(sg[k], lw1[k * HID + tid], acc);
    acc = acc > 0.f ? acc : expm1f(acc);
    sh[tid] = acc * lw2[tid];
    __syncthreads();
    for (int off = 64; off >= 1; off >>= 1) {
        if (tid < off) sh[tid] += sh[tid + off];
        __syncthreads();
    }
    if (tid == 0) out[g] = sh[0] + lb2[0];
}

extern "C" void kernel_launch(void* const* d_in, const int* in_sizes, int n_in,
                              void* d_out, int out_size, void* d_ws, size_t ws_size,
                              hipStream_t stream) {
    const float* x    = (const float*)d_in[0];
    const int*   ei   = (const int*)d_in[1];
    const int*   batch= (const int*)d_in[2];
    const float* W1   = (const float*)d_in[3];
    const float* as1  = (const float*)d_in[4];
    const float* ad1  = (const float*)d_in[5];
    const float* b1   = (const float*)d_in[6];
    const float* W2   = (const float*)d_in[7];
    const float* as2  = (const float*)d_in[8];
    const float* ad2  = (const float*)d_in[9];
    const float* b2   = (const float*)d_in[10];
    const float* lw1  = (const float*)d_in[11];
    const float* lb1  = (const float*)d_in[12];
    const float* lw2  = (const float*)d_in[13];
    const float* lb2  = (const float*)d_in[14];
    float* out = (float*)d_out;

    // workspace layout (~73 MB); colv has +1024-int pad for pipelined preloads
    unsigned int* REC = (unsigned int*)d_ws;         // N*32 uints = 128B records (12.8 MB)
    float* B    = (float*)(REC + (size_t)NN * 32);   // N*64 fp32 (25.6 MB)
    float* aD1  = B + (size_t)NN * 64;               // N*8
    float* aD2  = aD1 + (size_t)NN * 8;              // N
    float* pool = aD2 + NN;                          // G*64
    float* cnt  = pool + GG * 64;                    // G
    int* rbeg   = (int*)(cnt + GG);                  // N
    int* rend   = rbeg + NN;                         // N
    int* cursor = rend + NN;                         // BINS
    int* bucket = cursor + BINS;                     // BINS*BCAP (15.0 MB)
    int* colv   = bucket + (size_t)BINS * BCAP;      // BINS*BCAP + pad

    const int* srcv = ei;
    const int* dstv = ei + EE;

    hipMemsetAsync(cursor, 0, BINS * sizeof(int), stream);
    hipMemsetAsync(pool, 0, (size_t)(GG * 64 + GG) * sizeof(float), stream);

    // FUSED: lin1 GEMM (391 long blocks, first) + bucket scatter (1563 short)
    k_fused<<<NGB + BKBLK, 256, 0, stream>>>(srcv, dstv, cursor, bucket,
                                             x, W1, as1, ad1, REC, aD1);
    k_binCSR<<<BINS, 256, 0, stream>>>(cursor, bucket, colv, rbeg, rend);

    // layer 1 aggregation
    k_gat_agg1<<<NN / 8, 256, 0, stream>>>(rbeg, rend, colv, REC, aD1, b1, B);

    // layer 2 (lin2 overwrites REC with layer-2 records; stream-ordered)
    k_lin2    <<<NGB, 256, 0, stream>>>(B, W2, as2, ad2, REC, aD2);
    k_gat_agg2<<<NN / 8, 256, 0, stream>>>(rbeg, rend, colv, REC, aD2, b2, batch, pool, cnt);

    // MLP head
    k_mlp<<<GG, 128, 0, stream>>>(pool, cnt, lw1, lb1, lw2, lb2, out);
}